// Round 12
// baseline (2411.327 us; speedup 1.0000x reference)
//
#include <hip/hip_runtime.h>
#include <hip/hip_fp16.h>
#include <math.h>

#define NN 8192
#define MM 64
#define BB 128
#define HIDC 512
#define OUTC 256
#define SEQW 63

#define CHUNKS 64        // p1: 64 blocks/batch, 128 rows each (256 thr)
#define CH2    32        // p2/p3: 32 blocks/batch, 256 rows each (256 thr)

// ---- workspace layout (float offsets) ----
#define OFF_KR    0
#define OFF_KW    8192
#define OFF_PR    16384
#define OFF_PW    17408
#define OFF_BS    18432                    // per-b 8: [2]=dd2 [3]=dkr [4]=swr
#define OFF_D     19456
#define OFF_PMSUM 27648                    // B*64*64
#define OFF_POUT  551936                   // B*32*64
#define OFF_DOTW  814080                   // B*N each below
#define OFF_DOTR  1862656
#define OFF_RN2   2911232
#define OFF_DOTD  3959808
#define OFF_WR    6056960
#define OFF_CNT   7105536                  // int counters: cnt1[128], cnt2[128]
#define OFF_HB    8388608                  // fp16 bank copy: B*N*M halves (134 MB)

__device__ __forceinline__ float lrelu(float x){ return x > 0.f ? x : 0.01f*x; }
__device__ __forceinline__ float sigm(float x){ return 1.f/(1.f+__expf(-x)); }

typedef float fx4 __attribute__((ext_vector_type(4)));
__device__ __forceinline__ float4 ntload4(const float* p){
  fx4 v = __builtin_nontemporal_load((const fx4*)p);
  return make_float4(v.x, v.y, v.z, v.w);
}

__device__ __forceinline__ float2 h2f(unsigned u){
  __half2 h = *reinterpret_cast<__half2*>(&u);
  return __half22float2(h);
}

// reductions for 1024-thread blocks
__device__ float block_reduce_sum(float v, float* red) {
  for (int m = 32; m >= 1; m >>= 1) v += __shfl_xor(v, m);
  int wid = threadIdx.x >> 6;
  if ((threadIdx.x & 63) == 0) red[wid] = v;
  __syncthreads();
  if (threadIdx.x == 0) { float s = 0.f; for (int i = 0; i < 16; ++i) s += red[i]; red[0] = s; }
  __syncthreads();
  float r = red[0];
  __syncthreads();
  return r;
}

__device__ float2 block_reduce_sum2(float2 v, float* red) {
  for (int m = 32; m >= 1; m >>= 1) { v.x += __shfl_xor(v.x, m); v.y += __shfl_xor(v.y, m); }
  int wid = threadIdx.x >> 6;
  if ((threadIdx.x & 63) == 0) { red[wid] = v.x; red[16 + wid] = v.y; }
  __syncthreads();
  if (threadIdx.x == 0) {
    float sx = 0.f, sy = 0.f;
    for (int i = 0; i < 16; ++i) { sx += red[i]; sy += red[16 + i]; }
    red[0] = sx; red[16] = sy;
  }
  __syncthreads();
  float2 r = make_float2(red[0], red[16]);
  __syncthreads();
  return r;
}

// ---------------- controller MLP + counter zeroing ----------------
__global__ __launch_bounds__(512) void ctrl_kernel(
    const float* __restrict__ x,
    const float* __restrict__ W0, const float* __restrict__ b0,
    const float* __restrict__ W1, const float* __restrict__ b1,
    const float* __restrict__ Wc, const float* __restrict__ bc,
    const float* __restrict__ Wr, const float* __restrict__ br,
    const float* __restrict__ Ww, const float* __restrict__ bw,
    float* __restrict__ ws, int* __restrict__ cnt)
{
  int b = blockIdx.x, t = threadIdx.x;
  __shared__ float xs[64];
  __shared__ float h0[512];
  __shared__ float h1[512];
  __shared__ float ct[256];
  __shared__ float rr[70], rw[70];
  if (t == 0) { cnt[b] = 0; cnt[BB + b] = 0; }   // zero closers' counters every launch
  if (t < 64) xs[t] = x[b*64 + t];
  __syncthreads();
  float acc = b0[t];
  for (int i = 0; i < 64; ++i) acc += xs[i] * W0[i*HIDC + t];
  h0[t] = lrelu(acc);
  __syncthreads();
  acc = b1[t];
  for (int i = 0; i < 512; ++i) acc += h0[i] * W1[i*HIDC + t];
  h1[t] = lrelu(acc);
  __syncthreads();
  if (t < 256) {
    acc = bc[t];
    for (int i = 0; i < 512; ++i) acc += h1[i] * Wc[i*OUTC + t];
    ct[t] = lrelu(acc);
  }
  __syncthreads();
  if (t < 70) {
    float ar = br[t], aw = bw[t];
    for (int i = 0; i < 256; ++i) { float c = ct[i]; ar += c * Wr[i*70 + t]; aw += c * Ww[i*70 + t]; }
    rr[t] = ar; rw[t] = aw;
  }
  __syncthreads();
  if (t < 64) { ws[OFF_KR + b*64 + t] = rr[t]; ws[OFF_KW + b*64 + t] = rw[t]; }
  if (t == 0) {
    float* p = ws + OFF_PR + b*8;
    p[0] = fmaxf(rr[64], 0.f) + 1e-8f;
    p[1] = sigm(rr[65]);
    float m = fmaxf(rr[66], fmaxf(rr[67], rr[68]));
    float e0 = expf(rr[66]-m), e1 = expf(rr[67]-m), e2 = expf(rr[68]-m);
    float ss = e0+e1+e2;
    p[2] = e0/ss; p[3] = e1/ss; p[4] = e2/ss;
    p[5] = fmaxf(rr[69], 0.f) + 1.f;
    float n2 = 0.f; for (int i = 0; i < 64; ++i) n2 += rr[i]*rr[i];
    p[6] = sqrtf(n2);
  }
  if (t == 1) {
    float* p = ws + OFF_PW + b*8;
    p[0] = fmaxf(rw[64], 0.f) + 1e-8f;
    p[1] = sigm(rw[65]);
    float m = fmaxf(rw[66], fmaxf(rw[67], rw[68]));
    float e0 = expf(rw[66]-m), e1 = expf(rw[67]-m), e2 = expf(rw[68]-m);
    float ss = e0+e1+e2;
    p[2] = e0/ss; p[3] = e1/ss; p[4] = e2/ss;
    p[5] = fmaxf(rw[69], 0.f) + 1.f;
    float n2 = 0.f; for (int i = 0; i < 64; ++i) n2 += rw[i]*rw[i];
    p[6] = sqrtf(n2);
  }
}

// ---------------- pass 1 (+ ea closer): f32 bank (nt) -> dots + fp16 copy; last block per batch does ea ----------------
__global__ __launch_bounds__(256, 4) void bank_pass1(const float* __restrict__ bank,
                                                     const float* __restrict__ Wea,
                                                     const float* __restrict__ bea,
                                                     float* __restrict__ ws,
                                                     ushort* __restrict__ hbank,
                                                     int* __restrict__ cnt)
{
  int blk = blockIdx.x;
  int b  = blk >> 6;              // 64 chunks per batch
  int ch = blk & 63;
  int n0 = ch << 7;               // 128 rows per block
  int t = threadIdx.x;
  int cg = t & 15;                // 16 lanes/row, 4 floats each
  int rl = t >> 4;                // 0..15
  __shared__ float kwS[64], krS[64], msum[64];
  __shared__ float cat[128], eaS[128], dS[64];
  __shared__ int oldc;
  if (t < 64) { kwS[t] = ws[OFF_KW + b*64 + t]; krS[t] = ws[OFF_KR + b*64 + t]; msum[t] = 0.f; }
  __syncthreads();
  float4 kw4 = *(float4*)&kwS[cg*4];
  float4 kr4 = *(float4*)&krS[cg*4];

  float4 v[8];
  #pragma unroll
  for (int it = 0; it < 8; ++it) {
    int n = n0 + rl + it*16;
    v[it] = ntload4(&bank[((size_t)b*NN + n)*MM + cg*4]);   // nt: never re-read, keep out of L3
  }
  // fp16 copy write (temporal: we WANT this resident in L3 for p2/p3)
  #pragma unroll
  for (int it = 0; it < 8; ++it) {
    int n = n0 + rl + it*16;
    __half2 ha = __floats2half2_rn(v[it].x, v[it].y);
    __half2 hb = __floats2half2_rn(v[it].z, v[it].w);
    uint2 hw;
    hw.x = *reinterpret_cast<unsigned*>(&ha);
    hw.y = *reinterpret_cast<unsigned*>(&hb);
    *(uint2*)&hbank[((size_t)b*NN + n)*MM + cg*4] = hw;
  }
  float dw[8], dr[8], r2[8];
  float m0=0.f, m1=0.f, m2=0.f, m3=0.f;
  #pragma unroll
  for (int it = 0; it < 8; ++it) {
    dw[it] = v[it].x*kw4.x + v[it].y*kw4.y + v[it].z*kw4.z + v[it].w*kw4.w;
    dr[it] = v[it].x*kr4.x + v[it].y*kr4.y + v[it].z*kr4.z + v[it].w*kr4.w;
    r2[it] = v[it].x*v[it].x + v[it].y*v[it].y + v[it].z*v[it].z + v[it].w*v[it].w;
    m0 += v[it].x; m1 += v[it].y; m2 += v[it].z; m3 += v[it].w;
  }
  #pragma unroll
  for (int m = 1; m < 16; m <<= 1) {
    #pragma unroll
    for (int it = 0; it < 8; ++it) {
      dw[it] += __shfl_xor(dw[it], m);
      dr[it] += __shfl_xor(dr[it], m);
      r2[it] += __shfl_xor(r2[it], m);
    }
  }
  if (cg == 0) {
    size_t base = (size_t)b*NN + n0 + rl;
    #pragma unroll
    for (int it = 0; it < 8; ++it) {
      ws[OFF_DOTW + base + it*16] = dw[it];
      ws[OFF_DOTR + base + it*16] = dr[it];
      ws[OFF_RN2  + base + it*16] = r2[it];
    }
  }
  atomicAdd(&msum[cg*4+0], m0);
  atomicAdd(&msum[cg*4+1], m1);
  atomicAdd(&msum[cg*4+2], m2);
  atomicAdd(&msum[cg*4+3], m3);
  __syncthreads();
  if (t < 64) ws[OFF_PMSUM + (size_t)(b*CHUNKS + ch)*64 + t] = msum[t];

  // ---- closer: last block of this batch computes ea (d, dd2, dkr) ----
  __threadfence();
  __syncthreads();
  if (t == 0) oldc = __hip_atomic_fetch_add(&cnt[b], 1, __ATOMIC_ACQ_REL, __HIP_MEMORY_SCOPE_AGENT);
  __syncthreads();
  if (oldc != CHUNKS - 1) return;
  __threadfence();

  if (t < 64) {
    float s = 0.f;
    for (int c2 = 0; c2 < CHUNKS; ++c2) s += ws[OFF_PMSUM + ((size_t)b*CHUNKS + c2)*64 + t];
    cat[t] = s * (1.0f/NN);
  } else if (t < 128) {
    cat[t] = kwS[t-64];
  }
  __syncthreads();
  if (t < 128) {
    float acc = bea[t];
    for (int i = 0; i < 128; ++i) acc += cat[i] * Wea[i*128 + t];
    eaS[t] = acc;
  }
  __syncthreads();
  if (t < 64) {
    float dv = eaS[64+t] - sigm(eaS[t]);
    dS[t] = dv;
    ws[OFF_D + b*64 + t] = dv;
  }
  __syncthreads();
  if (t < 64) {
    float dv = dS[t];
    float dd = dv*dv;
    float dk = dv * krS[t];
    #pragma unroll
    for (int m = 32; m >= 1; m >>= 1) { dd += __shfl_xor(dd, m); dk += __shfl_xor(dk, m); }
    if (t == 0) { ws[OFF_BS + b*8 + 2] = dd; ws[OFF_BS + b*8 + 3] = dk; }
  }
}

// ---------------- pass 2: fp16 bank -> dotd (REVERSE batch order) ----------------
__global__ __launch_bounds__(256, 4) void bank_pass2h(const ushort* __restrict__ hb, float* __restrict__ ws)
{
  int blk = blockIdx.x;           // BB*CH2
  int b  = (BB - 1) - (blk >> 5); // reversed: most recently written fp16 first
  int n0 = (blk & 31) << 8;       // 256 rows per block
  int t = threadIdx.x;
  int cg = t & 7;                 // 8 lanes/row, 8 halves each
  int rl = t >> 3;                // 0..31
  __shared__ float dS[64];
  if (t < 64) dS[t] = ws[OFF_D + b*64 + t];
  __syncthreads();
  float d8[8];
  #pragma unroll
  for (int j = 0; j < 8; ++j) d8[j] = dS[cg*8 + j];

  uint4 hv[8];
  #pragma unroll
  for (int it = 0; it < 8; ++it) {
    int n = n0 + rl + it*32;
    hv[it] = *(const uint4*)&hb[((size_t)b*NN + n)*MM + cg*8];
  }
  float dd[8];
  #pragma unroll
  for (int it = 0; it < 8; ++it) {
    float2 f0 = h2f(hv[it].x), f1 = h2f(hv[it].y), f2 = h2f(hv[it].z), f3 = h2f(hv[it].w);
    dd[it] = f0.x*d8[0] + f0.y*d8[1] + f1.x*d8[2] + f1.y*d8[3]
           + f2.x*d8[4] + f2.y*d8[5] + f3.x*d8[6] + f3.y*d8[7];
  }
  #pragma unroll
  for (int m = 1; m < 8; m <<= 1) {
    #pragma unroll
    for (int it = 0; it < 8; ++it) dd[it] += __shfl_xor(dd[it], m);
  }
  if (cg == 0) {
    size_t base = (size_t)b*NN + n0 + rl;
    #pragma unroll
    for (int it = 0; it < 8; ++it) ws[OFF_DOTD + base + it*32] = dd[it];
  }
}

// ---------------- combined addressing: write (ww -> LDS) then read (wr -> ws, swr) ----------------
__global__ __launch_bounds__(1024, 1) void address_wr(
    const float* __restrict__ wwprev, const float* __restrict__ wrprev,
    float* __restrict__ ws)
{
  int b = blockIdx.x, t = threadIdx.x;
  __shared__ float buf[NN];
  __shared__ float wwS[NN];
  __shared__ float red[32];
  const size_t bN = (size_t)b*NN;

  // ===== phase A: write addressing =====
  {
    const float4* wp4 = (const float4*)(wwprev + bN);
    float4 w0 = wp4[t], w1 = wp4[1024 + t];
    float lps = (w0.x+w0.y+w0.z+w0.w) + (w1.x+w1.y+w1.z+w1.w);

    const float* prm = ws + OFF_PW + b*8;
    float beta = prm[0], g = prm[1], s0 = prm[2], s1 = prm[3], s2 = prm[4], gamma = prm[5], knorm = prm[6];

    const float4* dw4 = (const float4*)(ws + OFF_DOTW + bN);
    const float4* rn4 = (const float4*)(ws + OFF_RN2  + bN);
    float4 dwl = dw4[t], dwh = dw4[1024 + t];
    float4 rnl = rn4[t], rnh = rn4[1024 + t];

    float lsum = 0.f;
    {
      float* dwlp = &dwl.x; float* dwhp = &dwh.x;
      float* rnlp = &rnl.x; float* rnhp = &rnh.x;
      #pragma unroll
      for (int j = 0; j < 4; ++j) {
        float cl = dwlp[j] / fmaxf(sqrtf(rnlp[j]) * knorm, 1e-8f);
        float chh = dwhp[j] / fmaxf(sqrtf(rnhp[j]) * knorm, 1e-8f);
        float el = __expf(beta * (cl - 1.f));
        float eh = __expf(beta * (chh - 1.f));
        buf[4*t + j] = el; buf[4096 + 4*t + j] = eh;
        lsum += el + eh;
      }
    }
    float2 se = block_reduce_sum2(make_float2(lps, lsum), red);
    float ie = g/se.y, ip = (1.f-g)/se.x;
    {
      float* w0p = &w0.x; float* w1p = &w1.x;
      #pragma unroll
      for (int j = 0; j < 4; ++j) {
        buf[4*t + j]        = buf[4*t + j]*ie        + w0p[j]*ip;
        buf[4096 + 4*t + j] = buf[4096 + 4*t + j]*ie + w1p[j]*ip;
      }
    }
    __syncthreads();
    float l2 = 0.f;
    float wpv[8];
    #pragma unroll
    for (int i = 0; i < 8; ++i) {
      int n = t + i*1024;
      float wsv = s0*buf[(n + NN - 1) & (NN-1)] + s1*buf[n] + s2*buf[(n + 1) & (NN-1)];
      float p = exp2f(gamma * log2f(wsv));
      wpv[i] = p; l2 += p;
    }
    float wpsum = block_reduce_sum(l2, red);
    float invp = 1.f/wpsum;
    #pragma unroll
    for (int i = 0; i < 8; ++i)
      wwS[t + i*1024] = wpv[i]*invp;    // ww stays in LDS — never touches global
  }
  __syncthreads();

  // ===== phase B: read addressing =====
  {
    const float4* wp4 = (const float4*)(wrprev + bN);
    float4 w0 = wp4[t], w1 = wp4[1024 + t];
    float lps = (w0.x+w0.y+w0.z+w0.w) + (w1.x+w1.y+w1.z+w1.w);

    const float* prm = ws + OFF_PR + b*8;
    float beta = prm[0], g = prm[1], s0 = prm[2], s1 = prm[3], s2 = prm[4], gamma = prm[5], knorm = prm[6];
    float dd2 = ws[OFF_BS + b*8 + 2], dkr = ws[OFF_BS + b*8 + 3];

    const float4* dr4 = (const float4*)(ws + OFF_DOTR + bN);
    const float4* rn4 = (const float4*)(ws + OFF_RN2  + bN);
    const float4* dd4 = (const float4*)(ws + OFF_DOTD + bN);
    float4 drl = dr4[t], drh = dr4[1024 + t];
    float4 rnl = rn4[t], rnh = rn4[1024 + t];
    float4 ddl = dd4[t], ddh = dd4[1024 + t];

    float lsum = 0.f;
    float el[4], eh[4];
    {
      float* drlp = &drl.x; float* drhp = &drh.x;
      float* rnlp = &rnl.x; float* rnhp = &rnh.x;
      float* ddlp = &ddl.x; float* ddhp = &ddh.x;
      #pragma unroll
      for (int j = 0; j < 4; ++j) {
        float wl = wwS[4*t + j], wh = wwS[4096 + 4*t + j];
        float dotl = drlp[j] + wl * dkr;
        float doth = drhp[j] + wh * dkr;
        float r2l = fmaxf(rnlp[j] + 2.f*wl*ddlp[j] + wl*wl*dd2, 0.f);
        float r2h = fmaxf(rnhp[j] + 2.f*wh*ddhp[j] + wh*wh*dd2, 0.f);
        float cl = dotl / fmaxf(sqrtf(r2l) * knorm, 1e-8f);
        float chh = doth / fmaxf(sqrtf(r2h) * knorm, 1e-8f);
        el[j] = __expf(beta * (cl - 1.f));
        eh[j] = __expf(beta * (chh - 1.f));
        lsum += el[j] + eh[j];
      }
    }
    float2 se = block_reduce_sum2(make_float2(lps, lsum), red);
    // buf still holds phase-A data until the barrier inside block_reduce... safe to overwrite now
    {
      float* w0p = &w0.x; float* w1p = &w1.x;
      float ie = g/se.y, ip = (1.f-g)/se.x;
      #pragma unroll
      for (int j = 0; j < 4; ++j) {
        buf[4*t + j]        = el[j]*ie + w0p[j]*ip;
        buf[4096 + 4*t + j] = eh[j]*ie + w1p[j]*ip;
      }
    }
    __syncthreads();
    float l2 = 0.f, lswr = 0.f;
    float wpv[8];
    #pragma unroll
    for (int i = 0; i < 8; ++i) {
      int n = t + i*1024;
      float wsv = s0*buf[(n + NN - 1) & (NN-1)] + s1*buf[n] + s2*buf[(n + 1) & (NN-1)];
      float p = exp2f(gamma * log2f(wsv));
      wpv[i] = p; l2 += p;
      lswr += p * wwS[n];
    }
    float2 ps = block_reduce_sum2(make_float2(l2, lswr), red);
    float invp = 1.f/ps.x;
    #pragma unroll
    for (int i = 0; i < 8; ++i)
      ws[OFF_WR + bN + t + i*1024] = wpv[i]*invp;
    if (t == 0) ws[OFF_BS + b*8 + 4] = ps.y * invp;
  }
}

// ---------------- pass 3 (+ final closer): fp16 bank -> out partials; last block does head ----------------
__global__ __launch_bounds__(256, 4) void bank_pass3h(const ushort* __restrict__ hb,
                                                      const float* __restrict__ Wsp, const float* __restrict__ bsp,
                                                      const float* __restrict__ Wo,  const float* __restrict__ bo,
                                                      float* __restrict__ out,
                                                      float* __restrict__ ws,
                                                      int* __restrict__ cnt)
{
  int blk = blockIdx.x;           // BB*CH2
  int b  = blk >> 5;
  int ch = blk & 31;
  int n0 = ch << 8;               // 256 rows
  int t = threadIdx.x;
  int cg = t & 7, rl = t >> 3;
  __shared__ float osum[64];
  __shared__ float o[64], seq[512];
  __shared__ int oldc;
  if (t < 64) osum[t] = 0.f;
  __syncthreads();

  float wrv[8];
  #pragma unroll
  for (int it = 0; it < 8; ++it)
    wrv[it] = ws[OFF_WR + (size_t)b*NN + n0 + rl + it*32];
  uint4 hv[8];
  #pragma unroll
  for (int it = 0; it < 8; ++it) {
    int n = n0 + rl + it*32;
    hv[it] = *(const uint4*)&hb[((size_t)b*NN + n)*MM + cg*8];
  }
  float a[8];
  #pragma unroll
  for (int j = 0; j < 8; ++j) a[j] = 0.f;
  #pragma unroll
  for (int it = 0; it < 8; ++it) {
    float2 f0 = h2f(hv[it].x), f1 = h2f(hv[it].y), f2 = h2f(hv[it].z), f3 = h2f(hv[it].w);
    float w = wrv[it];
    a[0] += w*f0.x; a[1] += w*f0.y; a[2] += w*f1.x; a[3] += w*f1.y;
    a[4] += w*f2.x; a[5] += w*f2.y; a[6] += w*f3.x; a[7] += w*f3.y;
  }
  #pragma unroll
  for (int m = 8; m < 64; m <<= 1) {
    #pragma unroll
    for (int j = 0; j < 8; ++j) a[j] += __shfl_xor(a[j], m);
  }
  if ((t & 56) == 0) {
    #pragma unroll
    for (int j = 0; j < 8; ++j) atomicAdd(&osum[cg*8 + j], a[j]);
  }
  __syncthreads();
  if (t < 64) ws[OFF_POUT + (size_t)(b*CH2 + ch)*64 + t] = osum[t];

  // ---- closer: last block of this batch runs the output head ----
  __threadfence();
  __syncthreads();
  if (t == 0) oldc = __hip_atomic_fetch_add(&cnt[BB + b], 1, __ATOMIC_ACQ_REL, __HIP_MEMORY_SCOPE_AGENT);
  __syncthreads();
  if (oldc != CH2 - 1) return;
  __threadfence();

  if (t < 64) {
    float s = 0.f;
    for (int c2 = 0; c2 < CH2; ++c2) s += ws[OFF_POUT + ((size_t)b*CH2 + c2)*64 + t];
    float swr = ws[OFF_BS + b*8 + 4];
    o[t] = s + swr * ws[OFF_D + b*64 + t];
  }
  __syncthreads();
  #pragma unroll
  for (int r = 0; r < 2; ++r) {
    int idx = t + 256*r;
    float acc = bsp[idx];
    #pragma unroll 4
    for (int i = 0; i < 64; ++i) acc += o[i] * Wsp[i*HIDC + idx];
    seq[idx] = lrelu(acc);
  }
  __syncthreads();
  if (t < SEQW) {
    float acc = bo[t];
    for (int i = 0; i < HIDC; ++i) acc += seq[i] * Wo[i*SEQW + t];
    out[b*SEQW + t] = sigm(acc);
  }
}

extern "C" void kernel_launch(void* const* d_in, const int* in_sizes, int n_in,
                              void* d_out, int out_size, void* d_ws, size_t ws_size,
                              hipStream_t stream) {
  const float* x    = (const float*)d_in[0];
  const float* bank = (const float*)d_in[1];
  const float* wrp  = (const float*)d_in[2];
  const float* wwp  = (const float*)d_in[3];
  const float* W0   = (const float*)d_in[4];
  const float* b0   = (const float*)d_in[5];
  const float* W1   = (const float*)d_in[6];
  const float* b1   = (const float*)d_in[7];
  const float* Wc   = (const float*)d_in[8];
  const float* bc   = (const float*)d_in[9];
  const float* Wr   = (const float*)d_in[10];
  const float* br   = (const float*)d_in[11];
  const float* Ww   = (const float*)d_in[12];
  const float* bw   = (const float*)d_in[13];
  const float* Wea  = (const float*)d_in[14];
  const float* bea  = (const float*)d_in[15];
  const float* Wsp  = (const float*)d_in[16];
  const float* bsp  = (const float*)d_in[17];
  const float* Wo   = (const float*)d_in[18];
  const float* bo   = (const float*)d_in[19];
  float*  ws  = (float*)d_ws;
  int*    cnt = (int*)(ws + OFF_CNT);
  ushort* hb  = (ushort*)(ws + OFF_HB);
  float*  out = (float*)d_out;

  ctrl_kernel<<<BB, 512, 0, stream>>>(x, W0,b0, W1,b1, Wc,bc, Wr,br, Ww,bw, ws, cnt);
  bank_pass1<<<BB*CHUNKS, 256, 0, stream>>>(bank, Wea, bea, ws, hb, cnt);
  bank_pass2h<<<BB*CH2, 256, 0, stream>>>(hb, ws);
  address_wr<<<BB, 1024, 0, stream>>>(wwp, wrp, ws);
  bank_pass3h<<<BB*CH2, 256, 0, stream>>>(hb, Wsp, bsp, Wo, bo, out, ws, cnt);
}

// Round 13
// 212.114 us; speedup vs baseline: 11.3681x; 11.3681x over previous
//
#include <hip/hip_runtime.h>
#include <hip/hip_fp16.h>
#include <math.h>

#define NN 8192
#define MM 64
#define BB 128
#define HIDC 512
#define OUTC 256
#define SEQW 63

#define CHUNKS 64        // pass1: 64 blocks/batch, 128 rows each
#define CH2    32        // pass2/3: 32 blocks/batch, 256 rows each

// ---- workspace layout (float offsets) ----
#define OFF_KR    0
#define OFF_KW    8192
#define OFF_PR    16384
#define OFF_PW    17408
#define OFF_BS    18432                    // per-b 8: [2]=dd2 [3]=dkr [4]=swr
#define OFF_D     19456
#define OFF_PMSUM 27648                    // B*64*64
#define OFF_POUT  551936                   // B*32*64
#define OFF_DOTW  814080                   // B*N each below
#define OFF_DOTR  1862656
#define OFF_RN2   2911232
#define OFF_DOTD  3959808
#define OFF_WW    5008384
#define OFF_WR    6056960
#define OFF_HB    8388608                  // fp16 bank copy: B*N*M halves (134 MB)

__device__ __forceinline__ float lrelu(float x){ return x > 0.f ? x : 0.01f*x; }
__device__ __forceinline__ float sigm(float x){ return 1.f/(1.f+__expf(-x)); }

typedef float fx4 __attribute__((ext_vector_type(4)));
__device__ __forceinline__ float4 ntload4(const float* p){
  fx4 v = __builtin_nontemporal_load((const fx4*)p);
  return make_float4(v.x, v.y, v.z, v.w);
}

__device__ __forceinline__ float2 h2f(unsigned u){
  __half2 h = *reinterpret_cast<__half2*>(&u);
  return __half22float2(h);
}

// reductions for 1024-thread blocks (16 waves)
__device__ float block_reduce_sum(float v, float* red) {
  for (int m = 32; m >= 1; m >>= 1) v += __shfl_xor(v, m);
  int wid = threadIdx.x >> 6;
  if ((threadIdx.x & 63) == 0) red[wid] = v;
  __syncthreads();
  if (threadIdx.x == 0) { float s = 0.f; for (int i = 0; i < 16; ++i) s += red[i]; red[0] = s; }
  __syncthreads();
  float r = red[0];
  __syncthreads();
  return r;
}

__device__ float2 block_reduce_sum2(float2 v, float* red) {
  for (int m = 32; m >= 1; m >>= 1) { v.x += __shfl_xor(v.x, m); v.y += __shfl_xor(v.y, m); }
  int wid = threadIdx.x >> 6;
  if ((threadIdx.x & 63) == 0) { red[wid] = v.x; red[16 + wid] = v.y; }
  __syncthreads();
  if (threadIdx.x == 0) {
    float sx = 0.f, sy = 0.f;
    for (int i = 0; i < 16; ++i) { sx += red[i]; sy += red[16 + i]; }
    red[0] = sx; red[16] = sy;
  }
  __syncthreads();
  float2 r = make_float2(red[0], red[16]);
  __syncthreads();
  return r;
}

// ---------------- controller MLP ----------------
__global__ __launch_bounds__(512) void ctrl_kernel(
    const float* __restrict__ x,
    const float* __restrict__ W0, const float* __restrict__ b0,
    const float* __restrict__ W1, const float* __restrict__ b1,
    const float* __restrict__ Wc, const float* __restrict__ bc,
    const float* __restrict__ Wr, const float* __restrict__ br,
    const float* __restrict__ Ww, const float* __restrict__ bw,
    float* __restrict__ ws)
{
  int b = blockIdx.x, t = threadIdx.x;
  __shared__ float xs[64];
  __shared__ float h0[512];
  __shared__ float h1[512];
  __shared__ float ct[256];
  __shared__ float rr[70], rw[70];
  if (t < 64) xs[t] = x[b*64 + t];
  __syncthreads();
  float acc = b0[t];
  for (int i = 0; i < 64; ++i) acc += xs[i] * W0[i*HIDC + t];
  h0[t] = lrelu(acc);
  __syncthreads();
  acc = b1[t];
  for (int i = 0; i < 512; ++i) acc += h0[i] * W1[i*HIDC + t];
  h1[t] = lrelu(acc);
  __syncthreads();
  if (t < 256) {
    acc = bc[t];
    for (int i = 0; i < 512; ++i) acc += h1[i] * Wc[i*OUTC + t];
    ct[t] = lrelu(acc);
  }
  __syncthreads();
  if (t < 70) {
    float ar = br[t], aw = bw[t];
    for (int i = 0; i < 256; ++i) { float c = ct[i]; ar += c * Wr[i*70 + t]; aw += c * Ww[i*70 + t]; }
    rr[t] = ar; rw[t] = aw;
  }
  __syncthreads();
  if (t < 64) { ws[OFF_KR + b*64 + t] = rr[t]; ws[OFF_KW + b*64 + t] = rw[t]; }
  if (t == 0) {
    float* p = ws + OFF_PR + b*8;
    p[0] = fmaxf(rr[64], 0.f) + 1e-8f;
    p[1] = sigm(rr[65]);
    float m = fmaxf(rr[66], fmaxf(rr[67], rr[68]));
    float e0 = expf(rr[66]-m), e1 = expf(rr[67]-m), e2 = expf(rr[68]-m);
    float ss = e0+e1+e2;
    p[2] = e0/ss; p[3] = e1/ss; p[4] = e2/ss;
    p[5] = fmaxf(rr[69], 0.f) + 1.f;
    float n2 = 0.f; for (int i = 0; i < 64; ++i) n2 += rr[i]*rr[i];
    p[6] = sqrtf(n2);
  }
  if (t == 1) {
    float* p = ws + OFF_PW + b*8;
    p[0] = fmaxf(rw[64], 0.f) + 1e-8f;
    p[1] = sigm(rw[65]);
    float m = fmaxf(rw[66], fmaxf(rw[67], rw[68]));
    float e0 = expf(rw[66]-m), e1 = expf(rw[67]-m), e2 = expf(rw[68]-m);
    float ss = e0+e1+e2;
    p[2] = e0/ss; p[3] = e1/ss; p[4] = e2/ss;
    p[5] = fmaxf(rw[69], 0.f) + 1.f;
    float n2 = 0.f; for (int i = 0; i < 64; ++i) n2 += rw[i]*rw[i];
    p[6] = sqrtf(n2);
  }
}

// ---------------- pass 1: f32 bank (nt) -> dotw/dotr/rn2/msum + fp16 copy ----------------
__global__ __launch_bounds__(256, 4) void bank_pass1(const float* __restrict__ bank,
                                                     float* __restrict__ ws,
                                                     ushort* __restrict__ hbank)
{
  int blk = blockIdx.x;
  int b  = blk >> 6;              // 64 chunks per batch
  int ch = blk & 63;
  int n0 = ch << 7;               // 128 rows per block
  int t = threadIdx.x;
  int cg = t & 15;                // 16 lanes/row, 4 floats each
  int rl = t >> 4;                // 0..15
  __shared__ float kwS[64], krS[64], msum[64];
  if (t < 64) { kwS[t] = ws[OFF_KW + b*64 + t]; krS[t] = ws[OFF_KR + b*64 + t]; msum[t] = 0.f; }
  __syncthreads();
  float4 kw4 = *(float4*)&kwS[cg*4];
  float4 kr4 = *(float4*)&krS[cg*4];

  float4 v[8];
  #pragma unroll
  for (int it = 0; it < 8; ++it) {
    int n = n0 + rl + it*16;
    v[it] = ntload4(&bank[((size_t)b*NN + n)*MM + cg*4]);   // nt: never re-read, keep out of L3
  }
  // fp16 copy write (temporal: we WANT this resident in L3 for p2/p3)
  #pragma unroll
  for (int it = 0; it < 8; ++it) {
    int n = n0 + rl + it*16;
    __half2 ha = __floats2half2_rn(v[it].x, v[it].y);
    __half2 hb = __floats2half2_rn(v[it].z, v[it].w);
    uint2 hw;
    hw.x = *reinterpret_cast<unsigned*>(&ha);
    hw.y = *reinterpret_cast<unsigned*>(&hb);
    *(uint2*)&hbank[((size_t)b*NN + n)*MM + cg*4] = hw;
  }
  float dw[8], dr[8], r2[8];
  float m0=0.f, m1=0.f, m2=0.f, m3=0.f;
  #pragma unroll
  for (int it = 0; it < 8; ++it) {
    dw[it] = v[it].x*kw4.x + v[it].y*kw4.y + v[it].z*kw4.z + v[it].w*kw4.w;
    dr[it] = v[it].x*kr4.x + v[it].y*kr4.y + v[it].z*kr4.z + v[it].w*kr4.w;
    r2[it] = v[it].x*v[it].x + v[it].y*v[it].y + v[it].z*v[it].z + v[it].w*v[it].w;
    m0 += v[it].x; m1 += v[it].y; m2 += v[it].z; m3 += v[it].w;
  }
  #pragma unroll
  for (int m = 1; m < 16; m <<= 1) {
    #pragma unroll
    for (int it = 0; it < 8; ++it) {
      dw[it] += __shfl_xor(dw[it], m);
      dr[it] += __shfl_xor(dr[it], m);
      r2[it] += __shfl_xor(r2[it], m);
    }
  }
  if (cg == 0) {
    size_t base = (size_t)b*NN + n0 + rl;
    #pragma unroll
    for (int it = 0; it < 8; ++it) {
      ws[OFF_DOTW + base + it*16] = dw[it];
      ws[OFF_DOTR + base + it*16] = dr[it];
      ws[OFF_RN2  + base + it*16] = r2[it];
    }
  }
  atomicAdd(&msum[cg*4+0], m0);
  atomicAdd(&msum[cg*4+1], m1);
  atomicAdd(&msum[cg*4+2], m2);
  atomicAdd(&msum[cg*4+3], m3);
  __syncthreads();
  if (t < 64) ws[OFF_PMSUM + (size_t)(b*CHUNKS + ch)*64 + t] = msum[t];
}

// ---------------- addr0: ea prefix + write addressing (float4 global phases) ----------------
__global__ __launch_bounds__(1024, 1) void address0(
    const float* __restrict__ wprev,
    const float* __restrict__ Wea, const float* __restrict__ bea,
    float* __restrict__ ws)
{
  int b = blockIdx.x, t = threadIdx.x;
  __shared__ float buf[NN];
  __shared__ float red[32];
  __shared__ float cat[128], eaS[128], dS[64];
  const size_t bN = (size_t)b*NN;

  // f4 ownership: elements 4t..4t+3 (lo) and 4096+4t..4096+4t+3 (hi)
  const float4* wp4 = (const float4*)(wprev + bN);
  float4 w0 = wp4[t], w1 = wp4[1024 + t];
  float lps = (w0.x+w0.y+w0.z+w0.w) + (w1.x+w1.y+w1.z+w1.w);

  // ea prefix
  if (t < 64) {
    float s = 0.f;
    for (int ch = 0; ch < CHUNKS; ++ch) s += ws[OFF_PMSUM + ((size_t)b*CHUNKS + ch)*64 + t];
    cat[t] = s * (1.0f/NN);
  } else if (t < 128) {
    cat[t] = ws[OFF_KW + b*64 + (t-64)];
  }
  __syncthreads();
  if (t < 128) {
    float acc = bea[t];
    for (int i = 0; i < 128; ++i) acc += cat[i] * Wea[i*128 + t];
    eaS[t] = acc;
  }
  __syncthreads();
  if (t < 64) {
    float dv = eaS[64+t] - sigm(eaS[t]);
    dS[t] = dv;
    ws[OFF_D + b*64 + t] = dv;
  }
  __syncthreads();
  if (t < 64) {   // wave-parallel dd2/dkr (was t==0 serial loop)
    float dv = dS[t];
    float dd = dv*dv;
    float dk = dv * ws[OFF_KR + b*64 + t];
    #pragma unroll
    for (int m = 32; m >= 1; m >>= 1) { dd += __shfl_xor(dd, m); dk += __shfl_xor(dk, m); }
    if (t == 0) { ws[OFF_BS + b*8 + 2] = dd; ws[OFF_BS + b*8 + 3] = dk; }
  }

  const float* prm = ws + OFF_PW + b*8;
  float beta = prm[0], g = prm[1], s0 = prm[2], s1 = prm[3], s2 = prm[4], gamma = prm[5], knorm = prm[6];

  const float4* dw4 = (const float4*)(ws + OFF_DOTW + bN);
  const float4* rn4 = (const float4*)(ws + OFF_RN2  + bN);
  float4 dwl = dw4[t], dwh = dw4[1024 + t];
  float4 rnl = rn4[t], rnh = rn4[1024 + t];

  float lsum = 0.f;
  {
    float el[4], eh[4];
    float* dwlp = &dwl.x; float* dwhp = &dwh.x;
    float* rnlp = &rnl.x; float* rnhp = &rnh.x;
    #pragma unroll
    for (int j = 0; j < 4; ++j) {
      float cl = dwlp[j] / fmaxf(sqrtf(rnlp[j]) * knorm, 1e-8f);
      float chh = dwhp[j] / fmaxf(sqrtf(rnhp[j]) * knorm, 1e-8f);
      el[j] = __expf(beta * (cl - 1.f));
      eh[j] = __expf(beta * (chh - 1.f));
      lsum += el[j] + eh[j];
    }
    #pragma unroll
    for (int j = 0; j < 4; ++j) { buf[4*t + j] = el[j]; buf[4096 + 4*t + j] = eh[j]; }
  }
  float2 se = block_reduce_sum2(make_float2(lps, lsum), red);
  float ie = g/se.y, ip = (1.f-g)/se.x;
  {
    float* w0p = &w0.x; float* w1p = &w1.x;
    #pragma unroll
    for (int j = 0; j < 4; ++j) {
      buf[4*t + j]        = buf[4*t + j]*ie        + w0p[j]*ip;
      buf[4096 + 4*t + j] = buf[4096 + 4*t + j]*ie + w1p[j]*ip;
    }
  }
  __syncthreads();
  // conv + sharpen: scalar conflict-free ownership (n = t + i*1024)
  float l2 = 0.f;
  float wpv[8];
  #pragma unroll
  for (int i = 0; i < 8; ++i) {
    int n = t + i*1024;
    float wsv = s0*buf[(n + NN - 1) & (NN-1)] + s1*buf[n] + s2*buf[(n + 1) & (NN-1)];
    float p = exp2f(gamma * log2f(wsv));
    wpv[i] = p; l2 += p;
  }
  float wpsum = block_reduce_sum(l2, red);
  float invp = 1.f/wpsum;
  #pragma unroll
  for (int i = 0; i < 8; ++i)
    ws[OFF_WW + bN + t + i*1024] = wpv[i]*invp;
}

// ---------------- pass 2: fp16 bank -> dotd (REVERSE batch order) ----------------
__global__ __launch_bounds__(256, 4) void bank_pass2h(const ushort* __restrict__ hb, float* __restrict__ ws)
{
  int blk = blockIdx.x;           // BB*CH2
  int b  = (BB - 1) - (blk >> 5); // reversed: most recently written fp16 first
  int n0 = (blk & 31) << 8;       // 256 rows per block
  int t = threadIdx.x;
  int cg = t & 7;                 // 8 lanes/row, 8 halves each
  int rl = t >> 3;                // 0..31
  __shared__ float dS[64];
  if (t < 64) dS[t] = ws[OFF_D + b*64 + t];
  __syncthreads();
  float d8[8];
  #pragma unroll
  for (int j = 0; j < 8; ++j) d8[j] = dS[cg*8 + j];

  uint4 hv[8];
  #pragma unroll
  for (int it = 0; it < 8; ++it) {
    int n = n0 + rl + it*32;
    hv[it] = *(const uint4*)&hb[((size_t)b*NN + n)*MM + cg*8];
  }
  float dd[8];
  #pragma unroll
  for (int it = 0; it < 8; ++it) {
    float2 f0 = h2f(hv[it].x), f1 = h2f(hv[it].y), f2 = h2f(hv[it].z), f3 = h2f(hv[it].w);
    dd[it] = f0.x*d8[0] + f0.y*d8[1] + f1.x*d8[2] + f1.y*d8[3]
           + f2.x*d8[4] + f2.y*d8[5] + f3.x*d8[6] + f3.y*d8[7];
  }
  #pragma unroll
  for (int m = 1; m < 8; m <<= 1) {
    #pragma unroll
    for (int it = 0; it < 8; ++it) dd[it] += __shfl_xor(dd[it], m);
  }
  if (cg == 0) {
    size_t base = (size_t)b*NN + n0 + rl;
    #pragma unroll
    for (int it = 0; it < 8; ++it) ws[OFF_DOTD + base + it*32] = dd[it];
  }
}

// ---------------- addr1: read addressing (float4 global phases, ww stashed in LDS) ----------------
__global__ __launch_bounds__(1024, 1) void address1(
    const float* __restrict__ wprev, float* __restrict__ ws)
{
  int b = blockIdx.x, t = threadIdx.x;
  __shared__ float buf[NN];
  __shared__ float wwS[NN];
  __shared__ float red[32];
  const size_t bN = (size_t)b*NN;

  const float4* wp4 = (const float4*)(wprev + bN);
  float4 w0 = wp4[t], w1 = wp4[1024 + t];
  float lps = (w0.x+w0.y+w0.z+w0.w) + (w1.x+w1.y+w1.z+w1.w);

  const float* prm = ws + OFF_PR + b*8;
  float beta = prm[0], g = prm[1], s0 = prm[2], s1 = prm[3], s2 = prm[4], gamma = prm[5], knorm = prm[6];
  float dd2 = ws[OFF_BS + b*8 + 2], dkr = ws[OFF_BS + b*8 + 3];

  const float4* ww4 = (const float4*)(ws + OFF_WW  + bN);
  const float4* dr4 = (const float4*)(ws + OFF_DOTR + bN);
  const float4* rn4 = (const float4*)(ws + OFF_RN2  + bN);
  const float4* dd4 = (const float4*)(ws + OFF_DOTD + bN);
  float4 wwl = ww4[t], wwh = ww4[1024 + t];
  float4 drl = dr4[t], drh = dr4[1024 + t];
  float4 rnl = rn4[t], rnh = rn4[1024 + t];
  float4 ddl = dd4[t], ddh = dd4[1024 + t];

  float lsum = 0.f;
  {
    float* wwlp = &wwl.x; float* wwhp = &wwh.x;
    float* drlp = &drl.x; float* drhp = &drh.x;
    float* rnlp = &rnl.x; float* rnhp = &rnh.x;
    float* ddlp = &ddl.x; float* ddhp = &ddh.x;
    #pragma unroll
    for (int j = 0; j < 4; ++j) {
      float wl = wwlp[j], wh = wwhp[j];
      float dotl = drlp[j] + wl * dkr;
      float doth = drhp[j] + wh * dkr;
      float r2l = fmaxf(rnlp[j] + 2.f*wl*ddlp[j] + wl*wl*dd2, 0.f);
      float r2h = fmaxf(rnhp[j] + 2.f*wh*ddhp[j] + wh*wh*dd2, 0.f);
      float cl = dotl / fmaxf(sqrtf(r2l) * knorm, 1e-8f);
      float chh = doth / fmaxf(sqrtf(r2h) * knorm, 1e-8f);
      float el = __expf(beta * (cl - 1.f));
      float eh = __expf(beta * (chh - 1.f));
      buf[4*t + j] = el; buf[4096 + 4*t + j] = eh;
      wwS[4*t + j] = wl; wwS[4096 + 4*t + j] = wh;
      lsum += el + eh;
    }
  }
  float2 se = block_reduce_sum2(make_float2(lps, lsum), red);
  float ie = g/se.y, ip = (1.f-g)/se.x;
  {
    float* w0p = &w0.x; float* w1p = &w1.x;
    #pragma unroll
    for (int j = 0; j < 4; ++j) {
      buf[4*t + j]        = buf[4*t + j]*ie        + w0p[j]*ip;
      buf[4096 + 4*t + j] = buf[4096 + 4*t + j]*ie + w1p[j]*ip;
    }
  }
  __syncthreads();
  float l2 = 0.f, lswr = 0.f;
  float wpv[8];
  #pragma unroll
  for (int i = 0; i < 8; ++i) {
    int n = t + i*1024;
    float wsv = s0*buf[(n + NN - 1) & (NN-1)] + s1*buf[n] + s2*buf[(n + 1) & (NN-1)];
    float p = exp2f(gamma * log2f(wsv));
    wpv[i] = p; l2 += p;
    lswr += p * wwS[n];
  }
  float2 ps = block_reduce_sum2(make_float2(l2, lswr), red);
  float invp = 1.f/ps.x;
  #pragma unroll
  for (int i = 0; i < 8; ++i)
    ws[OFF_WR + bN + t + i*1024] = wpv[i]*invp;
  if (t == 0) ws[OFF_BS + b*8 + 4] = ps.y * invp;
}

// ---------------- pass 3: fp16 bank -> out partials ----------------
__global__ __launch_bounds__(256, 4) void bank_pass3h(const ushort* __restrict__ hb, float* __restrict__ ws)
{
  int blk = blockIdx.x;           // BB*CH2
  int b  = blk >> 5;
  int ch = blk & 31;
  int n0 = ch << 8;               // 256 rows
  int t = threadIdx.x;
  int cg = t & 7, rl = t >> 3;
  __shared__ float osum[64];
  if (t < 64) osum[t] = 0.f;
  __syncthreads();

  float wrv[8];
  #pragma unroll
  for (int it = 0; it < 8; ++it)
    wrv[it] = ws[OFF_WR + (size_t)b*NN + n0 + rl + it*32];
  uint4 hv[8];
  #pragma unroll
  for (int it = 0; it < 8; ++it) {
    int n = n0 + rl + it*32;
    hv[it] = *(const uint4*)&hb[((size_t)b*NN + n)*MM + cg*8];
  }
  float a[8];
  #pragma unroll
  for (int j = 0; j < 8; ++j) a[j] = 0.f;
  #pragma unroll
  for (int it = 0; it < 8; ++it) {
    float2 f0 = h2f(hv[it].x), f1 = h2f(hv[it].y), f2 = h2f(hv[it].z), f3 = h2f(hv[it].w);
    float w = wrv[it];
    a[0] += w*f0.x; a[1] += w*f0.y; a[2] += w*f1.x; a[3] += w*f1.y;
    a[4] += w*f2.x; a[5] += w*f2.y; a[6] += w*f3.x; a[7] += w*f3.y;
  }
  #pragma unroll
  for (int m = 8; m < 64; m <<= 1) {
    #pragma unroll
    for (int j = 0; j < 8; ++j) a[j] += __shfl_xor(a[j], m);
  }
  if ((t & 56) == 0) {
    #pragma unroll
    for (int j = 0; j < 8; ++j) atomicAdd(&osum[cg*8 + j], a[j]);
  }
  __syncthreads();
  if (t < 64) ws[OFF_POUT + (size_t)(b*CH2 + ch)*64 + t] = osum[t];
}

// ---------------- final head ----------------
__global__ __launch_bounds__(512) void final_kernel(
    const float* __restrict__ Wsp, const float* __restrict__ bsp,
    const float* __restrict__ Wo,  const float* __restrict__ bo,
    float* __restrict__ out, float* __restrict__ ws)
{
  int b = blockIdx.x, t = threadIdx.x;
  __shared__ float o[64], seq[512];
  if (t < 64) {
    float s = 0.f;
    for (int ch = 0; ch < CH2; ++ch) s += ws[OFF_POUT + ((size_t)b*CH2 + ch)*64 + t];
    float swr = ws[OFF_BS + b*8 + 4];
    o[t] = s + swr * ws[OFF_D + b*64 + t];
  }
  __syncthreads();
  float acc = bsp[t];
  for (int i = 0; i < 64; ++i) acc += o[i] * Wsp[i*HIDC + t];
  seq[t] = lrelu(acc);
  __syncthreads();
  if (t < SEQW) {
    float a = bo[t];
    for (int i = 0; i < 512; ++i) a += seq[i] * Wo[i*SEQW + t];
    out[b*SEQW + t] = sigm(a);
  }
}

extern "C" void kernel_launch(void* const* d_in, const int* in_sizes, int n_in,
                              void* d_out, int out_size, void* d_ws, size_t ws_size,
                              hipStream_t stream) {
  const float* x    = (const float*)d_in[0];
  const float* bank = (const float*)d_in[1];
  const float* wrp  = (const float*)d_in[2];
  const float* wwp  = (const float*)d_in[3];
  const float* W0   = (const float*)d_in[4];
  const float* b0   = (const float*)d_in[5];
  const float* W1   = (const float*)d_in[6];
  const float* b1   = (const float*)d_in[7];
  const float* Wc   = (const float*)d_in[8];
  const float* bc   = (const float*)d_in[9];
  const float* Wr   = (const float*)d_in[10];
  const float* br   = (const float*)d_in[11];
  const float* Ww   = (const float*)d_in[12];
  const float* bw   = (const float*)d_in[13];
  const float* Wea  = (const float*)d_in[14];
  const float* bea  = (const float*)d_in[15];
  const float* Wsp  = (const float*)d_in[16];
  const float* bsp  = (const float*)d_in[17];
  const float* Wo   = (const float*)d_in[18];
  const float* bo   = (const float*)d_in[19];
  float*  ws  = (float*)d_ws;
  ushort* hb  = (ushort*)(ws + OFF_HB);
  float*  out = (float*)d_out;

  ctrl_kernel<<<BB, 512, 0, stream>>>(x, W0,b0, W1,b1, Wc,bc, Wr,br, Ww,bw, ws);
  bank_pass1<<<BB*CHUNKS, 256, 0, stream>>>(bank, ws, hb);
  address0<<<BB, 1024, 0, stream>>>(wwp, Wea, bea, ws);
  bank_pass2h<<<BB*CH2, 256, 0, stream>>>(hb, ws);
  address1<<<BB, 1024, 0, stream>>>(wrp, ws);
  bank_pass3h<<<BB*CH2, 256, 0, stream>>>(hb, ws);
  final_kernel<<<BB, 512, 0, stream>>>(Wsp,bsp, Wo,bo, out, ws);
}